// Round 2
// baseline (198.537 us; speedup 1.0000x reference)
//
#include <hip/hip_runtime.h>

// SGC on MI355X, algebraically collapsed:
//   out[g] = sum_{n in g} (A_hat^2 (x @ (W1@W2)))[n] + cnt_g*(b1.W2) + b2
// Fold W1@W2 -> v[75]; reduce nodes to scalars u = dis * (x.v); each hop:
//   s[c] = sum_{edges r->c} u[r]   (scalar gather + atomic)
//   u    = dis^2 * (s + u)          (self-loop folded, elementwise)
// Final: y2 = dis*(s+u), pooled by graph id.
// NOTE: harness delivers integer inputs as int32 (edge_index, batch).

#define NNODES 50000
#define NEDGES 800000
#define NGRAPHS 512
#define FDIM 75
#define HDIM 128

__global__ void k_setup(const float* __restrict__ W1, const float* __restrict__ b1,
                        const float* __restrict__ W2, const float* __restrict__ b2,
                        float* __restrict__ v, float* __restrict__ cb) {
    int t = threadIdx.x;
    if (t < FDIM) {
        float s = 0.f;
        #pragma unroll 8
        for (int j = 0; j < HDIM; ++j) s += W1[t * HDIM + j] * W2[j];
        v[t] = s;
    } else if (t == FDIM) {
        float s = 0.f;
        for (int j = 0; j < HDIM; ++j) s += b1[j] * W2[j];
        cb[0] = s;        // c = b1 . W2 (per-node constant added at pool)
        cb[1] = b2[0];
    }
}

// deg = 1 (self-loop), s = 0
__global__ void k_init(float* __restrict__ deg, float* __restrict__ s, int n) {
    int i = blockIdx.x * blockDim.x + threadIdx.x;
    if (i < n) { deg[i] = 1.0f; s[i] = 0.0f; }
}

__global__ void k_deg_acc(const int* __restrict__ col, float* __restrict__ deg, int e) {
    int i = blockIdx.x * blockDim.x + threadIdx.x;
    if (i < e) atomicAdd(&deg[col[i]], 1.0f);
}

__global__ void k_dis(float* __restrict__ deg, int n) {
    int i = blockIdx.x * blockDim.x + threadIdx.x;
    if (i < n) deg[i] = rsqrtf(deg[i]);   // deg >= 1 always
}

// u[i] = dis[i] * dot(x[i,:], v)
__global__ void k_u0(const float* __restrict__ x, const float* __restrict__ v,
                     const float* __restrict__ dis, float* __restrict__ u, int n) {
    __shared__ float sv[FDIM];
    if (threadIdx.x < FDIM) sv[threadIdx.x] = v[threadIdx.x];
    __syncthreads();
    int i = blockIdx.x * blockDim.x + threadIdx.x;
    if (i < n) {
        const float* xi = x + (size_t)i * FDIM;
        float s = 0.f;
        #pragma unroll 5
        for (int j = 0; j < FDIM; ++j) s += xi[j] * sv[j];
        u[i] = dis[i] * s;
    }
}

// s[col] += u[row]
__global__ void k_edge(const int* __restrict__ row, const int* __restrict__ col,
                       const float* __restrict__ u, float* __restrict__ s, int e) {
    int i = blockIdx.x * blockDim.x + threadIdx.x;
    if (i < e) atomicAdd(&s[col[i]], u[row[i]]);
}

// u = dis^2*(s+u);  s = 0 (ready for next hop)
__global__ void k_hop_finish(const float* __restrict__ dis, float* __restrict__ s,
                             float* __restrict__ u, int n) {
    int i = blockIdx.x * blockDim.x + threadIdx.x;
    if (i < n) {
        float d = dis[i];
        u[i] = d * d * (s[i] + u[i]);
        s[i] = 0.0f;
    }
}

__global__ void k_out_init(const float* __restrict__ cb, float* __restrict__ out, int g) {
    int i = blockIdx.x * blockDim.x + threadIdx.x;
    if (i < g) out[i] = cb[1];   // b2
}

// out[batch[i]] += dis[i]*(s[i]+u[i]) + cb[0]
__global__ void k_pool(const int* __restrict__ batch, const float* __restrict__ dis,
                       const float* __restrict__ s, const float* __restrict__ u,
                       const float* __restrict__ cb, float* __restrict__ out, int n) {
    int i = blockIdx.x * blockDim.x + threadIdx.x;
    if (i < n) atomicAdd(&out[batch[i]], dis[i] * (s[i] + u[i]) + cb[0]);
}

extern "C" void kernel_launch(void* const* d_in, const int* in_sizes, int n_in,
                              void* d_out, int out_size, void* d_ws, size_t ws_size,
                              hipStream_t stream) {
    const float* x   = (const float*)d_in[0];
    const int*   ei  = (const int*)d_in[1];   // [2, E] int32 (harness converts ints)
    const int*   bat = (const int*)d_in[2];   // [N] int32
    const float* W1  = (const float*)d_in[3];
    const float* b1  = (const float*)d_in[4];
    const float* W2  = (const float*)d_in[5];
    const float* b2  = (const float*)d_in[6];
    float* out = (float*)d_out;

    const int* row = ei;            // edge_index[0]
    const int* col = ei + NEDGES;   // edge_index[1]

    // workspace: 3N + 136 floats ~ 600KB
    float* ws  = (float*)d_ws;
    float* v   = ws;              // 128 (75 used)
    float* cb  = ws + 128;        // 8 (2 used)
    float* dis = ws + 136;        // N (deg, then rsqrt in place)
    float* u   = dis + NNODES;    // N
    float* s   = u + NNODES;      // N

    const int B = 256;
    const int gN = (NNODES + B - 1) / B;
    const int gE = (NEDGES + B - 1) / B;

    k_setup<<<1, 128, 0, stream>>>(W1, b1, W2, b2, v, cb);
    k_init<<<gN, B, 0, stream>>>(dis, s, NNODES);
    k_deg_acc<<<gE, B, 0, stream>>>(col, dis, NEDGES);
    k_dis<<<gN, B, 0, stream>>>(dis, NNODES);
    k_u0<<<gN, B, 0, stream>>>(x, v, dis, u, NNODES);

    k_edge<<<gE, B, 0, stream>>>(row, col, u, s, NEDGES);        // hop 1 scatter
    k_hop_finish<<<gN, B, 0, stream>>>(dis, s, u, NNODES);       // u1; s=0
    k_edge<<<gE, B, 0, stream>>>(row, col, u, s, NEDGES);        // hop 2 scatter

    k_out_init<<<1, NGRAPHS, 0, stream>>>(cb, out, NGRAPHS);
    k_pool<<<gN, B, 0, stream>>>(bat, dis, s, u, cb, out, NNODES);
}

// Round 3
// 174.981 us; speedup vs baseline: 1.1346x; 1.1346x over previous
//
#include <hip/hip_runtime.h>

// SGC, algebraically collapsed: out[g] = sum_{n in g} (A_hat^2 (x@(W1@W2)))[n]
//                                        + cnt_g*(b1.W2) + b2
// u = dis * y;  per hop: S[c] = sum_{r->c} u[r];  u' = dis^2 * (S + u).
// Scatter passes use LDS privatization (2 ranges x 25000 f32 bins = 100KB LDS)
// + dense per-block partials + tree reduce -> no global fp atomics on the
// 800K-edge passes (round-2 showed those run at a ~16G atomic/s wall, 49us each).

#define NNODES 50000
#define NEDGES 800000
#define NGRAPHS 512
#define FDIM 75
#define HDIM 128
#define HALFB 25000   // bins per range; 2 ranges cover 50000 nodes

// ---- setup: v = W1@W2 (75), cb[0] = b1.W2, out[g] = b2 ----
__global__ void k_setup(const float* __restrict__ W1, const float* __restrict__ b1,
                        const float* __restrict__ W2, const float* __restrict__ b2,
                        float* __restrict__ v, float* __restrict__ cb,
                        float* __restrict__ out) {
    int t = threadIdx.x;
    if (t < FDIM) {
        float s = 0.f;
        #pragma unroll 8
        for (int j = 0; j < HDIM; ++j) s += W1[t * HDIM + j] * W2[j];
        v[t] = s;
    } else if (t == FDIM) {
        float s = 0.f;
        for (int j = 0; j < HDIM; ++j) s += b1[j] * W2[j];
        cb[0] = s;
    }
    if (t >= 128 && t < 128 + NGRAPHS) out[t - 128] = b2[0];
}

// ---- LDS-privatized scatter: partial[(half*C+b)][bin] = per-chunk segment sum
// WITH_VAL=0: histogram of col (value 1.0).  WITH_VAL=1: value u[row[e]].
template <int WITH_VAL>
__global__ __launch_bounds__(256)
void k_scatter(const int* __restrict__ col, const int* __restrict__ row,
               const float* __restrict__ u, float* __restrict__ partial,
               int C, int chunk) {
    __shared__ float h[HALFB];
    for (int i = threadIdx.x; i < HALFB; i += 256) h[i] = 0.f;
    __syncthreads();
    const int b = blockIdx.x;
    const int half = blockIdx.y;
    const int lo = half * HALFB;
    int base = b * chunk;
    int end = base + chunk; if (end > NEDGES) end = NEDGES;
    #pragma unroll 4
    for (int e = base + threadIdx.x; e < end; e += 256) {
        unsigned c = (unsigned)(col[e] - lo);
        if (c < (unsigned)HALFB) {
            float val = WITH_VAL ? u[row[e]] : 1.0f;
            atomicAdd(&h[c], val);   // ds_add_f32, no fabric traffic
        }
    }
    __syncthreads();
    float* p = partial + (size_t)(half * C + b) * HALFB;
    for (int i = threadIdx.x; i < HALFB; i += 256) p[i] = h[i];
}

// ---- reduce deg partials -> dis, and u0 = dis * (x.v) fused ----
__global__ void k_dis_u0(const float* __restrict__ partial, const float* __restrict__ x,
                         const float* __restrict__ v, float* __restrict__ dis,
                         float* __restrict__ u, int C) {
    __shared__ float sv[FDIM];
    if (threadIdx.x < FDIM) sv[threadIdx.x] = v[threadIdx.x];
    __syncthreads();
    int i = blockIdx.x * blockDim.x + threadIdx.x;
    if (i >= NNODES) return;
    int half = i / HALFB, loc = i - half * HALFB;
    const float* p = partial + (size_t)half * C * HALFB + loc;
    float s = 1.f;   // self-loop
    for (int b = 0; b < C; ++b) s += p[(size_t)b * HALFB];
    float d = rsqrtf(s);
    dis[i] = d;
    const float* xi = x + (size_t)i * FDIM;
    float acc = 0.f;
    #pragma unroll 5
    for (int j = 0; j < FDIM; ++j) acc += xi[j] * sv[j];
    u[i] = d * acc;
}

// ---- reduce hop partials: u = dis^2 * (S + u) ----
__global__ void k_finish_hop(const float* __restrict__ partial, const float* __restrict__ dis,
                             float* __restrict__ u, int C) {
    int i = blockIdx.x * blockDim.x + threadIdx.x;
    if (i >= NNODES) return;
    int half = i / HALFB, loc = i - half * HALFB;
    const float* p = partial + (size_t)half * C * HALFB + loc;
    float s = 0.f;
    for (int b = 0; b < C; ++b) s += p[(size_t)b * HALFB];
    float d = dis[i];
    u[i] = d * d * (s + u[i]);
}

// ---- final reduce + pool: y = dis*(S+u)+cb0; out[batch] += y (wave-segmented) ----
__global__ void k_finish_pool(const float* __restrict__ partial, const float* __restrict__ dis,
                              const float* __restrict__ u, const int* __restrict__ batch,
                              const float* __restrict__ cb, float* __restrict__ out, int C) {
    int i = blockIdx.x * blockDim.x + threadIdx.x;
    float y = 0.f; int g = -1;
    if (i < NNODES) {
        int half = i / HALFB, loc = i - half * HALFB;
        const float* p = partial + (size_t)half * C * HALFB + loc;
        float s = 0.f;
        for (int b = 0; b < C; ++b) s += p[(size_t)b * HALFB];
        y = dis[i] * (s + u[i]) + cb[0];
        g = batch[i];
    }
    int g0 = __shfl(g, 0), g63 = __shfl(g, 63);
    if (g0 == g63 && g0 >= 0) {
        // batch is sorted -> whole wave same graph; one atomic per wave
        for (int o = 32; o; o >>= 1) y += __shfl_down(y, o);
        if ((threadIdx.x & 63) == 0) atomicAdd(&out[g0], y);
    } else if (g >= 0) {
        atomicAdd(&out[g], y);
    }
}

// ================= fallback (round-2 atomic path, used only if ws too small) ==
__global__ void f_init(float* deg, float* s, int n) {
    int i = blockIdx.x * blockDim.x + threadIdx.x;
    if (i < n) { deg[i] = 1.0f; s[i] = 0.0f; }
}
__global__ void f_deg_acc(const int* __restrict__ col, float* deg, int e) {
    int i = blockIdx.x * blockDim.x + threadIdx.x;
    if (i < e) atomicAdd(&deg[col[i]], 1.0f);
}
__global__ void f_dis(float* deg, int n) {
    int i = blockIdx.x * blockDim.x + threadIdx.x;
    if (i < n) deg[i] = rsqrtf(deg[i]);
}
__global__ void f_u0(const float* __restrict__ x, const float* __restrict__ v,
                     const float* __restrict__ dis, float* u, int n) {
    __shared__ float sv[FDIM];
    if (threadIdx.x < FDIM) sv[threadIdx.x] = v[threadIdx.x];
    __syncthreads();
    int i = blockIdx.x * blockDim.x + threadIdx.x;
    if (i < n) {
        const float* xi = x + (size_t)i * FDIM;
        float s = 0.f;
        for (int j = 0; j < FDIM; ++j) s += xi[j] * sv[j];
        u[i] = dis[i] * s;
    }
}
__global__ void f_edge(const int* __restrict__ row, const int* __restrict__ col,
                       const float* __restrict__ u, float* s, int e) {
    int i = blockIdx.x * blockDim.x + threadIdx.x;
    if (i < e) atomicAdd(&s[col[i]], u[row[i]]);
}
__global__ void f_hop_finish(const float* __restrict__ dis, float* s, float* u, int n) {
    int i = blockIdx.x * blockDim.x + threadIdx.x;
    if (i < n) { float d = dis[i]; u[i] = d * d * (s[i] + u[i]); s[i] = 0.0f; }
}
__global__ void f_pool(const int* __restrict__ batch, const float* __restrict__ dis,
                       const float* __restrict__ s, const float* __restrict__ u,
                       const float* __restrict__ cb, float* out, int n) {
    int i = blockIdx.x * blockDim.x + threadIdx.x;
    if (i < n) atomicAdd(&out[batch[i]], dis[i] * (s[i] + u[i]) + cb[0]);
}
// =============================================================================

extern "C" void kernel_launch(void* const* d_in, const int* in_sizes, int n_in,
                              void* d_out, int out_size, void* d_ws, size_t ws_size,
                              hipStream_t stream) {
    const float* x   = (const float*)d_in[0];
    const int*   ei  = (const int*)d_in[1];   // [2,E] int32 (harness converts ints)
    const int*   bat = (const int*)d_in[2];   // [N] int32, sorted
    const float* W1  = (const float*)d_in[3];
    const float* b1  = (const float*)d_in[4];
    const float* W2  = (const float*)d_in[5];
    const float* b2  = (const float*)d_in[6];
    float* out = (float*)d_out;

    const int* row = ei;            // edge_index[0]
    const int* col = ei + NEDGES;   // edge_index[1]

    float* ws  = (float*)d_ws;
    float* v   = ws;              // 128
    float* cb  = ws + 128;        // 8
    float* dis = ws + 136;        // N
    float* u   = dis + NNODES;    // N
    float* rest = u + NNODES;     // partials (or fallback s)

    const size_t fixed_bytes = (size_t)(136 + 2 * NNODES) * sizeof(float);
    int C = 0;
    if (ws_size > fixed_bytes)
        C = (int)((ws_size - fixed_bytes) / ((size_t)2 * HALFB * sizeof(float)));
    if (C > 64) C = 64;

    const int B = 256;
    const int gN = (NNODES + B - 1) / B;

    if (C >= 8) {
        float* partial = rest;
        int chunk = (NEDGES + C - 1) / C;
        k_setup<<<1, 640, 0, stream>>>(W1, b1, W2, b2, v, cb, out);
        k_scatter<0><<<dim3(C, 2), B, 0, stream>>>(col, col, nullptr, partial, C, chunk);
        k_dis_u0<<<gN, B, 0, stream>>>(partial, x, v, dis, u, C);
        k_scatter<1><<<dim3(C, 2), B, 0, stream>>>(col, row, u, partial, C, chunk);
        k_finish_hop<<<gN, B, 0, stream>>>(partial, dis, u, C);
        k_scatter<1><<<dim3(C, 2), B, 0, stream>>>(col, row, u, partial, C, chunk);
        k_finish_pool<<<gN, B, 0, stream>>>(partial, dis, u, bat, cb, out, C);
    } else {
        // atomic fallback (round-2 behavior)
        float* s = rest;
        const int gE = (NEDGES + B - 1) / B;
        k_setup<<<1, 640, 0, stream>>>(W1, b1, W2, b2, v, cb, out);
        f_init<<<gN, B, 0, stream>>>(dis, s, NNODES);
        f_deg_acc<<<gE, B, 0, stream>>>(col, dis, NEDGES);
        f_dis<<<gN, B, 0, stream>>>(dis, NNODES);
        f_u0<<<gN, B, 0, stream>>>(x, v, dis, u, NNODES);
        f_edge<<<gE, B, 0, stream>>>(row, col, u, s, NEDGES);
        f_hop_finish<<<gN, B, 0, stream>>>(dis, s, u, NNODES);
        f_edge<<<gE, B, 0, stream>>>(row, col, u, s, NEDGES);
        f_pool<<<gN, B, 0, stream>>>(bat, dis, s, u, cb, out, NNODES);
    }
}

// Round 4
// 78.657 us; speedup vs baseline: 2.5241x; 2.2246x over previous
//
#include <hip/hip_runtime.h>

// SGC, algebraically collapsed: out[g] = sum_{n in g} (A_hat^2 (x@(W1@W2)))[n]
//                                        + cnt_g*(b1.W2) + b2
// Scalars: y0 = x.v; u0 = dis*y0; u1 = dis^2*(S1+u0), S1[c] = sum_{r->c} u0[r].
// Final hop fused with pooling (512 graph bins only):
//   out[g] = b2 + sum_{n in g}(dis[n]*u1[n] + b1.W2) + sum_{r->c, batch[c]=g} dis[c]*u1[r]
// -> only TWO per-node scatter passes (degree, hop1), both LDS-privatized:
//    R=4 ranges x 12500 bins (50KB LDS), C=64 chunks, 1024-thread blocks
//    (grid=256 = 1 block/CU, 4 waves/SIMD; round-3 had 1 wave/SIMD -> 48us).

#define NNODES 50000
#define NEDGES 800000
#define NGRAPHS 512
#define FDIM 75
#define HDIM 128

#define C_CHUNKS 64
#define R_RANGES 4
#define BINS 12500            // NNODES / R_RANGES
#define CHUNK 12500           // NEDGES / C_CHUNKS
#define SCAT_B 1024
#define POOL_BLOCKS 256

// ---- setup: v = W1@W2, cb[0] = b1.W2, cb[1] = b2 ----
__global__ void k_setup(const float* __restrict__ W1, const float* __restrict__ b1,
                        const float* __restrict__ W2, const float* __restrict__ b2,
                        float* __restrict__ v, float* __restrict__ cb) {
    int t = threadIdx.x;
    if (t < FDIM) {
        float s = 0.f;
        #pragma unroll 8
        for (int j = 0; j < HDIM; ++j) s += W1[t * HDIM + j] * W2[j];
        v[t] = s;
    } else if (t == FDIM) {
        float s = 0.f;
        for (int j = 0; j < HDIM; ++j) s += b1[j] * W2[j];
        cb[0] = s;
        cb[1] = b2[0];
    }
}

// ---- LDS-privatized per-node scatter (degree or hop1) ----
// block (c,r): scan edge chunk c, accumulate cols in range r into 50KB LDS,
// write dense partial. WITH_VAL=0 -> value 1.0 (degree); 1 -> u[row[e]].
template <int WITH_VAL>
__global__ __launch_bounds__(SCAT_B)
void k_scatter(const int* __restrict__ col, const int* __restrict__ row,
               const float* __restrict__ u, float* __restrict__ partial) {
    __shared__ float h[BINS];
    for (int i = threadIdx.x; i < BINS; i += SCAT_B) h[i] = 0.f;
    __syncthreads();
    const int c = blockIdx.x;
    const int lo = blockIdx.y * BINS;
    const int base = c * CHUNK;
    #pragma unroll 2
    for (int e = base + threadIdx.x; e < base + CHUNK; e += SCAT_B) {
        unsigned b = (unsigned)(col[e] - lo);
        if (b < (unsigned)BINS)
            atomicAdd(&h[b], WITH_VAL ? u[row[e]] : 1.0f);   // ds_add_f32
    }
    __syncthreads();
    float* p = partial + (size_t)c * NNODES + lo;
    for (int i = threadIdx.x; i < BINS; i += SCAT_B) p[i] = h[i];
}

// ---- reduce degree partials -> dis, kd={dis,batch}, u0 = dis*(x.v) ----
__global__ __launch_bounds__(256)
void k_dis_u0(const float* __restrict__ partial, const float* __restrict__ x,
              const float* __restrict__ v, const int* __restrict__ batch,
              float* __restrict__ dis, float2* __restrict__ kd, float* __restrict__ u) {
    __shared__ float sv[FDIM];
    if (threadIdx.x < FDIM) sv[threadIdx.x] = v[threadIdx.x];
    __syncthreads();
    int i = blockIdx.x * 256 + threadIdx.x;
    if (i >= NNODES) return;
    float s = 1.f;   // self-loop
    #pragma unroll 8
    for (int b = 0; b < C_CHUNKS; ++b) s += partial[(size_t)b * NNODES + i];
    float d = rsqrtf(s);
    dis[i] = d;
    kd[i] = make_float2(d, __int_as_float(batch[i]));
    const float* xi = x + (size_t)i * FDIM;
    float acc = 0.f;
    #pragma unroll 5
    for (int j = 0; j < FDIM; ++j) acc += xi[j] * sv[j];
    u[i] = d * acc;
}

// ---- reduce hop1 partials: u = dis^2 * (S1 + u) ----
__global__ __launch_bounds__(256)
void k_finish_hop(const float* __restrict__ partial, const float* __restrict__ dis,
                  float* __restrict__ u) {
    int i = blockIdx.x * 256 + threadIdx.x;
    if (i >= NNODES) return;
    float s = 0.f;
    #pragma unroll 8
    for (int b = 0; b < C_CHUNKS; ++b) s += partial[(size_t)b * NNODES + i];
    float d = dis[i];
    u[i] = d * d * (s + u[i]);
}

// ---- fused hop2 + pool: 512-bin LDS histogram per block ----
__global__ __launch_bounds__(512)
void k_hop2_pool(const int* __restrict__ col, const int* __restrict__ row,
                 const float2* __restrict__ kd, const float* __restrict__ u,
                 const float* __restrict__ cb, float* __restrict__ partial2) {
    __shared__ float h[NGRAPHS];
    for (int i = threadIdx.x; i < NGRAPHS; i += 512) h[i] = 0.f;
    __syncthreads();
    const int stride = POOL_BLOCKS * 512;
    const int tid = blockIdx.x * 512 + threadIdx.x;
    // edge term: h[batch[c]] += dis[c] * u1[r]
    for (int e = tid; e < NEDGES; e += stride) {
        float2 k = kd[col[e]];
        atomicAdd(&h[__float_as_int(k.y)], k.x * u[row[e]]);
    }
    // node term: h[batch[n]] += dis[n]*u1[n] + cb0  (batch sorted -> wave-aggregate)
    float cb0 = cb[0];
    for (int n = tid; n < NNODES; n += stride) {
        float2 k = kd[n];
        float val = k.x * u[n] + cb0;
        int g = __float_as_int(k.y);
        int g0 = __shfl(g, 0), g63 = __shfl(g, 63);
        if (g0 == g63) {
            for (int o = 32; o; o >>= 1) val += __shfl_down(val, o);
            if ((threadIdx.x & 63) == 0) atomicAdd(&h[g0], val);
        } else {
            atomicAdd(&h[g], val);
        }
    }
    __syncthreads();
    for (int i = threadIdx.x; i < NGRAPHS; i += 512)
        partial2[(size_t)blockIdx.x * NGRAPHS + i] = h[i];
}

// ---- final: out[g] = b2 + sum_b partial2[b][g] ----
__global__ __launch_bounds__(512)
void k_out(const float* __restrict__ partial2, const float* __restrict__ cb,
           float* __restrict__ out) {
    int g = threadIdx.x;
    if (g >= NGRAPHS) return;
    float s = cb[1];
    #pragma unroll 8
    for (int b = 0; b < POOL_BLOCKS; ++b) s += partial2[(size_t)b * NGRAPHS + g];
    out[g] = s;
}

// ================= fallback (round-2 atomic path, if ws too small) ==========
__global__ void f_init(float* deg, float* s, int n) {
    int i = blockIdx.x * blockDim.x + threadIdx.x;
    if (i < n) { deg[i] = 1.0f; s[i] = 0.0f; }
}
__global__ void f_deg_acc(const int* __restrict__ col, float* deg, int e) {
    int i = blockIdx.x * blockDim.x + threadIdx.x;
    if (i < e) atomicAdd(&deg[col[i]], 1.0f);
}
__global__ void f_dis(float* deg, int n) {
    int i = blockIdx.x * blockDim.x + threadIdx.x;
    if (i < n) deg[i] = rsqrtf(deg[i]);
}
__global__ void f_u0(const float* __restrict__ x, const float* __restrict__ v,
                     const float* __restrict__ dis, float* u, int n) {
    __shared__ float sv[FDIM];
    if (threadIdx.x < FDIM) sv[threadIdx.x] = v[threadIdx.x];
    __syncthreads();
    int i = blockIdx.x * blockDim.x + threadIdx.x;
    if (i < n) {
        const float* xi = x + (size_t)i * FDIM;
        float s = 0.f;
        for (int j = 0; j < FDIM; ++j) s += xi[j] * sv[j];
        u[i] = dis[i] * s;
    }
}
__global__ void f_edge(const int* __restrict__ row, const int* __restrict__ col,
                       const float* __restrict__ u, float* s, int e) {
    int i = blockIdx.x * blockDim.x + threadIdx.x;
    if (i < e) atomicAdd(&s[col[i]], u[row[i]]);
}
__global__ void f_hop_finish(const float* __restrict__ dis, float* s, float* u, int n) {
    int i = blockIdx.x * blockDim.x + threadIdx.x;
    if (i < n) { float d = dis[i]; u[i] = d * d * (s[i] + u[i]); s[i] = 0.0f; }
}
__global__ void f_out_init(const float* __restrict__ cb, float* out, int g) {
    int i = blockIdx.x * blockDim.x + threadIdx.x;
    if (i < g) out[i] = cb[1];
}
__global__ void f_pool(const int* __restrict__ batch, const float* __restrict__ dis,
                       const float* __restrict__ s, const float* __restrict__ u,
                       const float* __restrict__ cb, float* out, int n) {
    int i = blockIdx.x * blockDim.x + threadIdx.x;
    if (i < n) atomicAdd(&out[batch[i]], dis[i] * (s[i] + u[i]) + cb[0]);
}
// ============================================================================

extern "C" void kernel_launch(void* const* d_in, const int* in_sizes, int n_in,
                              void* d_out, int out_size, void* d_ws, size_t ws_size,
                              hipStream_t stream) {
    const float* x   = (const float*)d_in[0];
    const int*   ei  = (const int*)d_in[1];   // [2,E] int32 (harness converts ints)
    const int*   bat = (const int*)d_in[2];   // [N] int32, sorted
    const float* W1  = (const float*)d_in[3];
    const float* b1  = (const float*)d_in[4];
    const float* W2  = (const float*)d_in[5];
    const float* b2  = (const float*)d_in[6];
    float* out = (float*)d_out;

    const int* row = ei;            // edge_index[0]
    const int* col = ei + NEDGES;   // edge_index[1]

    // ws layout (floats): v 128 | cb 8 | dis N | u N | kd 2N (8B-aligned) |
    //                     partial C*N | partial2 POOL_BLOCKS*NGRAPHS
    float*  ws       = (float*)d_ws;
    float*  v        = ws;
    float*  cb       = ws + 128;
    float*  dis      = ws + 136;
    float*  u        = dis + NNODES;
    float2* kd       = (float2*)(u + NNODES);          // offset 136+2N: even -> 8B aligned
    float*  partial  = (float*)(kd + NNODES);
    float*  partial2 = partial + (size_t)C_CHUNKS * NNODES;

    const size_t need = ((size_t)136 + 4 * NNODES + (size_t)C_CHUNKS * NNODES
                         + (size_t)POOL_BLOCKS * NGRAPHS) * sizeof(float);

    const int gN256 = (NNODES + 255) / 256;

    if (ws_size >= need) {
        k_setup<<<1, 128, 0, stream>>>(W1, b1, W2, b2, v, cb);
        k_scatter<0><<<dim3(C_CHUNKS, R_RANGES), SCAT_B, 0, stream>>>(col, row, nullptr, partial);
        k_dis_u0<<<gN256, 256, 0, stream>>>(partial, x, v, bat, dis, kd, u);
        k_scatter<1><<<dim3(C_CHUNKS, R_RANGES), SCAT_B, 0, stream>>>(col, row, u, partial);
        k_finish_hop<<<gN256, 256, 0, stream>>>(partial, dis, u);
        k_hop2_pool<<<POOL_BLOCKS, 512, 0, stream>>>(col, row, kd, u, cb, partial2);
        k_out<<<1, 512, 0, stream>>>(partial2, cb, out);
    } else {
        // atomic fallback (round-2 behavior, needs 136+3N floats)
        float* s = (float*)(kd);   // reuse
        const int B = 256;
        const int gE = (NEDGES + B - 1) / B;
        k_setup<<<1, 128, 0, stream>>>(W1, b1, W2, b2, v, cb);
        f_init<<<gN256, B, 0, stream>>>(dis, s, NNODES);
        f_deg_acc<<<gE, B, 0, stream>>>(col, dis, NEDGES);
        f_dis<<<gN256, B, 0, stream>>>(dis, NNODES);
        f_u0<<<gN256, B, 0, stream>>>(x, v, dis, u, NNODES);
        f_edge<<<gE, B, 0, stream>>>(row, col, u, s, NEDGES);
        f_hop_finish<<<gN256, B, 0, stream>>>(dis, s, u, NNODES);
        f_out_init<<<1, NGRAPHS, 0, stream>>>(cb, out, NGRAPHS);
        f_edge<<<gE, B, 0, stream>>>(row, col, u, s, NEDGES);
        f_pool<<<gN256, B, 0, stream>>>(bat, dis, s, u, cb, out, NNODES);
    }
}

// Round 5
// 75.266 us; speedup vs baseline: 2.6378x; 1.0451x over previous
//
#include <hip/hip_runtime.h>

// SGC, algebraically collapsed: out[g] = sum_{n in g} (A_hat^2 (x@(W1@W2)))[n]
//                                        + cnt_g*(b1.W2) + b2
// Scalars: u0 = dis*(x.v); u1 = dis^2*(S1+u0) with S1[c] = sum_{r->c} u0[r];
// hop2 fused with 512-bin pooling. Per-node scatters (degree, hop1) run on
// edges PRE-BUCKETED by col-range (16 ranges x 3125 bins = 12.5KB LDS):
// no filter waste, 2 blocks/CU (8 waves/SIMD), partials only CP*N = 6.4MB.

#define NNODES 50000
#define NEDGES 800000
#define NGRAPHS 512
#define FDIM 75
#define HDIM 128

#define RR 16            // col ranges (buckets)
#define BINS 3125        // NNODES / RR
#define CP 32            // chunks (blocks) per range
#define CAP 55000        // bucket capacity (50000 expected +- ~220)
#define PB 1024          // scatter/partition block size
#define POOLB 256        // hop2_pool blocks
#define EPB 3125         // edges per partition block (NEDGES/256)

// ---- setup: v = W1@W2, cb[0]=b1.W2, cb[1]=b2, zero bucket cursors ----
__global__ void k_setup(const float* __restrict__ W1, const float* __restrict__ b1,
                        const float* __restrict__ W2, const float* __restrict__ b2,
                        float* __restrict__ v, float* __restrict__ cb,
                        int* __restrict__ cursor) {
    int t = threadIdx.x;
    if (t < FDIM) {
        float s = 0.f;
        #pragma unroll 8
        for (int j = 0; j < HDIM; ++j) s += W1[t * HDIM + j] * W2[j];
        v[t] = s;
    } else if (t == FDIM) {
        float s = 0.f;
        for (int j = 0; j < HDIM; ++j) s += b1[j] * W2[j];
        cb[0] = s;
        cb[1] = b2[0];
    }
    if (t >= 96 && t < 96 + RR) cursor[t - 96] = 0;
}

// ---- partition: bucket edges by col/BINS (order within bucket irrelevant) ----
__global__ __launch_bounds__(PB)
void k_partition(const int* __restrict__ col, const int* __restrict__ row,
                 int* __restrict__ cursor, int* __restrict__ bcol,
                 int* __restrict__ brow) {
    __shared__ int cnt[RR], base[RR];
    if (threadIdx.x < RR) cnt[threadIdx.x] = 0;
    __syncthreads();
    const int start = blockIdx.x * EPB;
    for (int i = threadIdx.x; i < EPB; i += PB)
        atomicAdd(&cnt[col[start + i] / BINS], 1);
    __syncthreads();
    if (threadIdx.x < RR) {
        base[threadIdx.x] = atomicAdd(&cursor[threadIdx.x], cnt[threadIdx.x]);
        cnt[threadIdx.x] = 0;
    }
    __syncthreads();
    for (int i = threadIdx.x; i < EPB; i += PB) {
        int c = col[start + i], r = row[start + i];
        int b = c / BINS;
        int k = atomicAdd(&cnt[b], 1);
        size_t idx = (size_t)b * CAP + base[b] + k;
        bcol[idx] = c;
        brow[idx] = r;
    }
}

// ---- bucketed LDS scatter; WITH_VAL=0: degree (1.0), 1: u[brow[e]] ----
template <int WITH_VAL>
__global__ __launch_bounds__(PB, 8)
void k_scatter_b(const int* __restrict__ cursor, const int* __restrict__ bcol,
                 const int* __restrict__ brow, const float* __restrict__ u,
                 float* __restrict__ partial) {
    __shared__ float h[BINS];
    for (int i = threadIdx.x; i < BINS; i += PB) h[i] = 0.f;
    const int r = blockIdx.y;
    const int cnt = cursor[r];
    const int chunk = (cnt + CP - 1) / CP;
    int s = blockIdx.x * chunk;
    int e = s + chunk; if (e > cnt) e = cnt;
    const int lo = r * BINS;
    const size_t bb = (size_t)r * CAP;
    __syncthreads();
    for (int i = s + threadIdx.x; i < e; i += PB) {
        int c = bcol[bb + i] - lo;
        atomicAdd(&h[c], WITH_VAL ? u[brow[bb + i]] : 1.0f);   // ds_add_f32
    }
    __syncthreads();
    float* p = partial + (size_t)blockIdx.x * NNODES + lo;
    for (int i = threadIdx.x; i < BINS; i += PB) p[i] = h[i];
}

// ---- reduce degree partials -> dis, kd={dis,batch}, u0 = dis*(x.v) ----
__global__ __launch_bounds__(256)
void k_dis_u0(const float* __restrict__ partial, const float* __restrict__ x,
              const float* __restrict__ v, const int* __restrict__ batch,
              float* __restrict__ dis, float2* __restrict__ kd, float* __restrict__ u) {
    __shared__ float sv[FDIM];
    if (threadIdx.x < FDIM) sv[threadIdx.x] = v[threadIdx.x];
    __syncthreads();
    int i = blockIdx.x * 256 + threadIdx.x;
    if (i >= NNODES) return;
    float s = 1.f;   // self-loop
    #pragma unroll 8
    for (int b = 0; b < CP; ++b) s += partial[(size_t)b * NNODES + i];
    float d = rsqrtf(s);
    dis[i] = d;
    kd[i] = make_float2(d, __int_as_float(batch[i]));
    const float* xi = x + (size_t)i * FDIM;
    float acc = 0.f;
    #pragma unroll 5
    for (int j = 0; j < FDIM; ++j) acc += xi[j] * sv[j];
    u[i] = d * acc;
}

// ---- reduce hop1 partials: u = dis^2 * (S1 + u) ----
__global__ __launch_bounds__(256)
void k_finish_hop(const float* __restrict__ partial, const float* __restrict__ dis,
                  float* __restrict__ u) {
    int i = blockIdx.x * 256 + threadIdx.x;
    if (i >= NNODES) return;
    float s = 0.f;
    #pragma unroll 8
    for (int b = 0; b < CP; ++b) s += partial[(size_t)b * NNODES + i];
    float d = dis[i];
    u[i] = d * d * (s + u[i]);
}

// ---- fused hop2 + pool: int4 edge loads, 512-bin LDS histogram ----
__global__ __launch_bounds__(PB)
void k_hop2_pool(const int* __restrict__ col, const int* __restrict__ row,
                 const float2* __restrict__ kd, const float* __restrict__ u,
                 const float* __restrict__ cb, float* __restrict__ partial2) {
    __shared__ float h[NGRAPHS];
    for (int i = threadIdx.x; i < NGRAPHS; i += PB) h[i] = 0.f;
    __syncthreads();
    const int tid = blockIdx.x * PB + threadIdx.x;
    // edge term: h[batch[c]] += dis[c]*u1[r]; 4 edges/thread, single shot
    if (tid < NEDGES / 4) {
        int4 c4 = ((const int4*)col)[tid];
        int4 r4 = ((const int4*)row)[tid];
        float2 k0 = kd[c4.x], k1 = kd[c4.y], k2 = kd[c4.z], k3 = kd[c4.w];
        float u0 = u[r4.x], u1v = u[r4.y], u2 = u[r4.z], u3 = u[r4.w];
        atomicAdd(&h[__float_as_int(k0.y)], k0.x * u0);
        atomicAdd(&h[__float_as_int(k1.y)], k1.x * u1v);
        atomicAdd(&h[__float_as_int(k2.y)], k2.x * u2);
        atomicAdd(&h[__float_as_int(k3.y)], k3.x * u3);
    }
    // node term: h[batch[n]] += dis[n]*u1[n] + cb0 (sorted -> wave-aggregate)
    {
        float cb0 = cb[0];
        float val = 0.f; int g = -1;
        if (tid < NNODES) {
            float2 k = kd[tid];
            val = k.x * u[tid] + cb0;
            g = __float_as_int(k.y);
        }
        int g0 = __shfl(g, 0), g63 = __shfl(g, 63);
        if (g0 == g63 && g0 >= 0) {
            for (int o = 32; o; o >>= 1) val += __shfl_down(val, o);
            if ((threadIdx.x & 63) == 0) atomicAdd(&h[g0], val);
        } else if (g >= 0) {
            atomicAdd(&h[g], val);
        }
    }
    __syncthreads();
    for (int i = threadIdx.x; i < NGRAPHS; i += PB)
        partial2[(size_t)blockIdx.x * NGRAPHS + i] = h[i];
}

// ---- final: out[g] = b2 + sum_b partial2[b][g] ----
__global__ __launch_bounds__(512)
void k_out(const float* __restrict__ partial2, const float* __restrict__ cb,
           float* __restrict__ out) {
    int g = threadIdx.x;
    if (g >= NGRAPHS) return;
    float s = cb[1];
    #pragma unroll 8
    for (int b = 0; b < POOLB; ++b) s += partial2[(size_t)b * NGRAPHS + g];
    out[g] = s;
}

// ================= fallback (round-2 atomic path, if ws too small) ==========
__global__ void f_init(float* deg, float* s, int n) {
    int i = blockIdx.x * blockDim.x + threadIdx.x;
    if (i < n) { deg[i] = 1.0f; s[i] = 0.0f; }
}
__global__ void f_deg_acc(const int* __restrict__ col, float* deg, int e) {
    int i = blockIdx.x * blockDim.x + threadIdx.x;
    if (i < e) atomicAdd(&deg[col[i]], 1.0f);
}
__global__ void f_dis(float* deg, int n) {
    int i = blockIdx.x * blockDim.x + threadIdx.x;
    if (i < n) deg[i] = rsqrtf(deg[i]);
}
__global__ void f_u0(const float* __restrict__ x, const float* __restrict__ v,
                     const float* __restrict__ dis, float* u, int n) {
    __shared__ float sv[FDIM];
    if (threadIdx.x < FDIM) sv[threadIdx.x] = v[threadIdx.x];
    __syncthreads();
    int i = blockIdx.x * blockDim.x + threadIdx.x;
    if (i < n) {
        const float* xi = x + (size_t)i * FDIM;
        float s = 0.f;
        for (int j = 0; j < FDIM; ++j) s += xi[j] * sv[j];
        u[i] = dis[i] * s;
    }
}
__global__ void f_edge(const int* __restrict__ row, const int* __restrict__ col,
                       const float* __restrict__ u, float* s, int e) {
    int i = blockIdx.x * blockDim.x + threadIdx.x;
    if (i < e) atomicAdd(&s[col[i]], u[row[i]]);
}
__global__ void f_hop_finish(const float* __restrict__ dis, float* s, float* u, int n) {
    int i = blockIdx.x * blockDim.x + threadIdx.x;
    if (i < n) { float d = dis[i]; u[i] = d * d * (s[i] + u[i]); s[i] = 0.0f; }
}
__global__ void f_out_init(const float* __restrict__ cb, float* out, int g) {
    int i = blockIdx.x * blockDim.x + threadIdx.x;
    if (i < g) out[i] = cb[1];
}
__global__ void f_pool(const int* __restrict__ batch, const float* __restrict__ dis,
                       const float* __restrict__ s, const float* __restrict__ u,
                       const float* __restrict__ cb, float* out, int n) {
    int i = blockIdx.x * blockDim.x + threadIdx.x;
    if (i < n) atomicAdd(&out[batch[i]], dis[i] * (s[i] + u[i]) + cb[0]);
}
// ============================================================================

extern "C" void kernel_launch(void* const* d_in, const int* in_sizes, int n_in,
                              void* d_out, int out_size, void* d_ws, size_t ws_size,
                              hipStream_t stream) {
    const float* x   = (const float*)d_in[0];
    const int*   ei  = (const int*)d_in[1];   // [2,E] int32 (harness converts ints)
    const int*   bat = (const int*)d_in[2];   // [N] int32, sorted
    const float* W1  = (const float*)d_in[3];
    const float* b1  = (const float*)d_in[4];
    const float* W2  = (const float*)d_in[5];
    const float* b2  = (const float*)d_in[6];
    float* out = (float*)d_out;

    const int* row = ei;            // edge_index[0]
    const int* col = ei + NEDGES;   // edge_index[1]

    // ws layout (floats): v 128 | cb 8 | cursor 16(int) | dis N | u N |
    //   kd 2N (8B aligned) | partial CP*N | partial2 POOLB*NGRAPHS | bcol | brow
    float*  ws       = (float*)d_ws;
    float*  v        = ws;
    float*  cb       = ws + 128;
    int*    cursor   = (int*)(ws + 136);
    float*  dis      = ws + 152;
    float*  u        = dis + NNODES;
    float2* kd       = (float2*)(u + NNODES);           // offset 152+2N: even
    float*  partial  = (float*)(kd + NNODES);
    float*  partial2 = partial + (size_t)CP * NNODES;
    int*    bcol     = (int*)(partial2 + (size_t)POOLB * NGRAPHS);
    int*    brow     = bcol + (size_t)RR * CAP;

    const size_t need = ((size_t)152 + 4 * NNODES + (size_t)CP * NNODES
                         + (size_t)POOLB * NGRAPHS + 2 * (size_t)RR * CAP)
                        * sizeof(float);

    const int gN256 = (NNODES + 255) / 256;

    if (ws_size >= need) {
        k_setup<<<1, 128, 0, stream>>>(W1, b1, W2, b2, v, cb, cursor);
        k_partition<<<NEDGES / EPB, PB, 0, stream>>>(col, row, cursor, bcol, brow);
        k_scatter_b<0><<<dim3(CP, RR), PB, 0, stream>>>(cursor, bcol, brow, nullptr, partial);
        k_dis_u0<<<gN256, 256, 0, stream>>>(partial, x, v, bat, dis, kd, u);
        k_scatter_b<1><<<dim3(CP, RR), PB, 0, stream>>>(cursor, bcol, brow, u, partial);
        k_finish_hop<<<gN256, 256, 0, stream>>>(partial, dis, u);
        k_hop2_pool<<<POOLB, PB, 0, stream>>>(col, row, kd, u, cb, partial2);
        k_out<<<1, 512, 0, stream>>>(partial2, cb, out);
    } else {
        // atomic fallback (round-2 behavior, needs 152+3N floats)
        float* s = (float*)kd;
        const int B = 256;
        const int gE = (NEDGES + B - 1) / B;
        k_setup<<<1, 128, 0, stream>>>(W1, b1, W2, b2, v, cb, cursor);
        f_init<<<gN256, B, 0, stream>>>(dis, s, NNODES);
        f_deg_acc<<<gE, B, 0, stream>>>(col, dis, NEDGES);
        f_dis<<<gN256, B, 0, stream>>>(dis, NNODES);
        f_u0<<<gN256, B, 0, stream>>>(x, v, dis, u, NNODES);
        f_edge<<<gE, B, 0, stream>>>(row, col, u, s, NEDGES);
        f_hop_finish<<<gN256, B, 0, stream>>>(dis, s, u, NNODES);
        f_out_init<<<1, NGRAPHS, 0, stream>>>(cb, out, NGRAPHS);
        f_edge<<<gE, B, 0, stream>>>(row, col, u, s, NEDGES);
        f_pool<<<gN256, B, 0, stream>>>(bat, dis, s, u, cb, out, NNODES);
    }
}